// Round 16
// baseline (160.898 us; speedup 1.0000x reference)
//
#include <hip/hip_runtime.h>
#include <hip/hip_bf16.h>
#include <cstdint>

#define IN_CH 512
#define OUT_CH 512
#define STYLE_DIM 512
#define BATCH 8
#define HW 64

typedef __bf16 bf16x8 __attribute__((ext_vector_type(8)));
typedef float f32x16 __attribute__((ext_vector_type(16)));

__device__ __forceinline__ void gload_lds16(const void* g, void* l) {
  __builtin_amdgcn_global_load_lds(
      (const __attribute__((address_space(1))) unsigned int*)g,
      (__attribute__((address_space(3))) unsigned int*)l,
      16, 0, 0);
}

#define WAITV(N) asm volatile("s_waitcnt vmcnt(" #N ")" ::: "memory")
#define BARRIER() do { asm volatile("" ::: "memory"); __builtin_amdgcn_s_barrier(); \
                       asm volatile("" ::: "memory"); } while (0)

// ---------------- kernel 1: style-GEMM (blocks 0..127) | zpg zero (block 128) ------------
__global__ void k_style(const float* __restrict__ style, const float* __restrict__ modw,
                        const float* __restrict__ modb, float* __restrict__ s_out,
                        float* __restrict__ zpg) {
  const int tid = threadIdx.x;
  if (blockIdx.x == 128) {
    float4 z = {0.f, 0.f, 0.f, 0.f};
    #pragma unroll
    for (int k = 0; k < 4; ++k) ((float4*)zpg)[tid * 4 + k] = z;
    return;
  }
  __shared__ float st[BATCH * STYLE_DIM];
  for (int i = tid; i < BATCH * STYLE_DIM; i += 256) st[i] = style[i];
  __syncthreads();
  const int ic = blockIdx.x * 4 + (tid >> 6);
  const int l = tid & 63;
  const float* mr = modw + (size_t)ic * STYLE_DIM + l * 8;
  float m[8];
  #pragma unroll
  for (int j = 0; j < 8; ++j) m[j] = mr[j];
  float accs[8];
  #pragma unroll
  for (int b = 0; b < 8; ++b) {
    const float* sb = st + b * STYLE_DIM + l * 8;
    float a = 0.f;
    #pragma unroll
    for (int j = 0; j < 8; ++j) a += m[j] * sb[j];
    accs[b] = a;
  }
  #pragma unroll
  for (int off = 32; off; off >>= 1) {
    #pragma unroll
    for (int b = 0; b < 8; ++b) accs[b] += __shfl_down(accs[b], off, 64);
  }
  if (l == 0) {
    #pragma unroll
    for (int b = 0; b < 8; ++b)
      s_out[b * IN_CH + ic] = accs[b] * 0.04419417382415922f + modb[ic];
  }
}

// ---------------- kernel 2 (fused): xprep | wprep | demod --------------------------------
// K=32 stripe layout (4-row 256B stripes): unit (j,p): R=4j+(p&3), slot s=((p>>2)-j)&3.
// Read algebra: pos=(R+4s)&15 -> same bijection family as the measured-0-conflict K=64 map.
__global__ void k_prep(const float* __restrict__ x, const float* __restrict__ s,
                       const float* __restrict__ w,
                       __bf16* __restrict__ xgp, __bf16* __restrict__ wgp,
                       float* __restrict__ scale) {
  const int t = threadIdx.x;
  const int bid = blockIdx.x;
  if (bid < 512) {
    // xgp[b][y][chunk16][272 units]: col=4*c4+(p&3) (0..67; data x=col-1), s=((p>>2)-c4)&3
    const int b = bid >> 6, y = bid & 63;
    const int xcol = t & 63;          // data x; col = xcol+1
    const int g0 = t >> 6;            // 0..7
    const float* sr = s + b * IN_CH;
    const size_t rowbase = ((size_t)(b * 64 + y)) * 16 * 272;
    #pragma unroll
    for (int i = 0; i < 8; ++i) {
      const int g = i * 8 + g0;       // chunk*4 + slot, 0..63
      bf16x8 pk;
      #pragma unroll
      for (int e = 0; e < 8; ++e) {
        const int ic = g * 8 + e;
        pk[e] = (__bf16)(x[(((size_t)(b * IN_CH) + ic) * HW + y) * HW + xcol] * sr[ic]);
      }
      const int col = xcol + 1, c4 = col >> 2;
      const int p = (col & 3) + 4 * (((g & 3) + c4) & 3);
      *(bf16x8*)(xgp + (rowbase + (size_t)(g >> 2) * 272 + c4 * 16 + p) * 8) = pk;
    }
    if (t < 256) {                    // halo cols 0,65,66,67 -> zeros
      const int hc = t & 3;
      const int col = hc ? 64 + hc : 0;
      const int g = t >> 2;           // 0..63
      const int c4 = col >> 2;
      const int p = (col & 3) + 4 * (((g & 3) + c4) & 3);
      bf16x8 z = {};
      *(bf16x8*)(xgp + (rowbase + (size_t)(g >> 2) * 272 + c4 * 16 + p) * 8) = z;
    }
  } else if (bid < 1024) {
    // wgp[tap][chunk16][octile4][512 units]
    const int idx = (bid - 512) * 512 + t;   // 262144
    const int oc = idx >> 9, ic = idx & 511;
    const int octile = oc >> 7;
    const int R = oc & 127, j = R >> 2, r = R & 3;
    const int chunk = ic >> 5;
    const int sl = (ic >> 3) & 3, e = ic & 7;
    const int p = r + 4 * ((sl + j) & 3);
    const int u = j * 16 + p;
    const float* pw = w + ((size_t)oc * IN_CH + ic) * 9;
    #pragma unroll
    for (int tp = 0; tp < 9; ++tp)
      wgp[((size_t)((tp * 16 + chunk) * 4 + octile) * 512 + u) * 8 + e] = (__bf16)pw[tp];
  } else {
    // demod-direct
    const int oc = (bid - 1024) * 8 + (t >> 6);
    const int l = t & 63;
    float w8[8];
    #pragma unroll
    for (int j = 0; j < 8; ++j) {
      const float* pw = w + ((size_t)oc * IN_CH + l * 8 + j) * 9;
      float sum = 0.f;
      #pragma unroll
      for (int tp = 0; tp < 9; ++tp) { float v = pw[tp]; sum += v * v; }
      w8[j] = sum;
    }
    #pragma unroll
    for (int b = 0; b < 8; ++b) {
      const float* sb = s + b * IN_CH + l * 8;
      float acc = 0.f;
      #pragma unroll
      for (int j = 0; j < 8; ++j) { float sv = sb[j]; acc += sv * sv * w8[j]; }
      #pragma unroll
      for (int off = 32; off; off >>= 1) acc += __shfl_down(acc, off, 64);
      if (l == 0)
        scale[b * OUT_CH + oc] =
            rsqrtf(acc * (1.0f / 4608.0f) + 1e-8f) * 0.014731391274719732f;
    }
  }
}

// ---------------- main conv: 128oc x 256px block, K=32, 2 blocks/CU ----------------------
// Same verified skeleton (conflict-free stripes, coalesced staging, counted vmcnt,
// triple-buffered W, tap unroll) at half LDS (53.2 KB) -> two co-resident blocks per CU;
// cross-block wave desync hides the per-tap barrier/ramp cost (m114 mechanism).
__global__ __launch_bounds__(256, 2) void k_conv(
    const __bf16* __restrict__ Wgp,  // [9][16][4][512*8]
    const __bf16* __restrict__ Xgp,  // [8][64][16][272*8]
    const float* __restrict__ scale, // [8][512] = demod*cs
    const __bf16* __restrict__ zpg,  // zeros (OOR/pad source)
    float* __restrict__ out)         // [8][512][64][64]
{
  __shared__ __attribute__((aligned(16))) __bf16 Xs[1792 * 8];    // 28672 B (1632 + pad)
  __shared__ __attribute__((aligned(16))) __bf16 Wl[3][512 * 8];  // 24576 B

  const int tid = threadIdx.x;
  const int lane = tid & 63;
  const int wn = tid >> 6;      // wave = image row 0..3; wave tile 128oc x 64px
  const int ln31 = lane & 31;
  const int laneK = lane >> 5;

  const int bid0 = blockIdx.x;
  const int bid = (bid0 & 7) * 64 + (bid0 >> 3);   // XCD-chunked: XCD x owns batch x
  const int b = bid >> 6;
  const int rem = bid & 63;
  const int ptile = rem >> 2;   // 0..15
  const int octile = rem & 3;   // 0..3
  const int r0 = ptile * 4;
  const int oc0 = octile * 128;

  auto stage_w = [&](int chunkv, int tapv, int bsel) {  // 2 instr/wave (8 KB)
    const __bf16* base = Wgp + (size_t)((tapv * 16 + chunkv) * 4 + octile) * (512 * 8);
    #pragma unroll
    for (int i = 0; i < 2; ++i) {
      const int u = i * 256 + tid;
      gload_lds16(base + (size_t)u * 8, (void*)((char*)Wl[bsel] + u * 16));
    }
  };
  auto stage_x = [&](int chunkv) {   // 7 instr/wave (units 0..1791; >=1632 junk from zpg)
    #pragma unroll
    for (int i = 0; i < 7; ++i) {
      const unsigned u = i * 256 + tid;
      const unsigned row = u / 272u;           // 0..6
      const unsigned rr = u - row * 272u;
      const int y = r0 - 1 + (int)row;
      const bool ok = (u < 1632u) & (y >= 0) & (y < HW);
      const __bf16* src = ok
          ? Xgp + (((size_t)(b * 64 + y) * 16 + chunkv) * 272 + rr) * 8
          : zpg;
      gload_lds16(src, (void*)((char*)Xs + u * 16));
    }
  };

  // prologue
  stage_x(0);               // X0(7)
  stage_w(0, 0, 0);         // +W0(2)
  stage_w(0, 1, 1);         // +W1(2) -> first tap's WAITV(2) drains X0+W0, keeps W1

  // ---- read addressing (loop-invariant, const-indexed) ----
  int aoffR[2];
  #pragma unroll
  for (int ksl = 0; ksl < 2; ++ksl)
    aoffR[ksl] = ((ln31 + 8 * ksl + 4 * laneK) & 15) * 8;
  int beleR[3][2];
  #pragma unroll
  for (int dxi = 0; dxi < 3; ++dxi) {
    const int col = ln31 + dxi;     // = ln31 + 1 + dx
    const int c4 = col >> 2;
    #pragma unroll
    for (int ksl = 0; ksl < 2; ++ksl) {
      const int pos = (col + 8 * ksl + 4 * laneK) & 15;
      beleR[dxi][ksl] = c4 * 128 + pos * 8;
    }
  }
  const __bf16* __restrict__ ab0 = Wl[0] + (ln31 >> 2) * 128;
  const __bf16* __restrict__ ab1 = Wl[1] + (ln31 >> 2) * 128;
  const __bf16* __restrict__ ab2 = Wl[2] + (ln31 >> 2) * 128;

  f32x16 acc[4][2] = {};

#define TAPBODY(T) { \
    if ((T) == 8 && c == 15) { WAITV(0); } else { WAITV(2); } \
    BARRIER(); \
    const __bf16* __restrict__ abase = ((T) % 3 == 0) ? ab0 : ((T) % 3 == 1) ? ab1 : ab2; \
    const __bf16* __restrict__ xbase = Xs + (wn + (T) / 3) * 2176; \
    _Pragma("unroll") \
    for (int ksl = 0; ksl < 2; ++ksl) { \
      const int ael = aoffR[ksl]; \
      const int bel = beleR[(T) % 3][ksl]; \
      bf16x8 av[4], bv[2]; \
      _Pragma("unroll") \
      for (int mf = 0; mf < 4; ++mf) av[mf] = *(const bf16x8*)(abase + mf * 1024 + ael); \
      bv[0] = *(const bf16x8*)(xbase + bel); \
      bv[1] = *(const bf16x8*)(xbase + 1024 + bel); \
      _Pragma("unroll") \
      for (int mf = 0; mf < 4; ++mf) { \
        acc[mf][0] = __builtin_amdgcn_mfma_f32_32x32x16_bf16(av[mf], bv[0], acc[mf][0], 0, 0, 0); \
        acc[mf][1] = __builtin_amdgcn_mfma_f32_32x32x16_bf16(av[mf], bv[1], acc[mf][1], 0, 0, 0); \
      } \
    } \
    if ((T) == 8) { \
      if (c < 15) { BARRIER(); stage_x(c + 1); stage_w(c + 1, 1, 1); } \
    } else if ((T) <= 6) { \
      stage_w(c, (T) + 2, ((T) + 2) % 3); \
    } else { /* T == 7 */ \
      if (c < 15) stage_w(c + 1, 0, 0); \
    } \
  }

  #pragma unroll 1
  for (int c = 0; c < 16; ++c) {
    TAPBODY(0) TAPBODY(1) TAPBODY(2)
    TAPBODY(3) TAPBODY(4) TAPBODY(5)
    TAPBODY(6) TAPBODY(7) TAPBODY(8)
  }

  // epilogue: out = acc * (demod*cs), NCHW
  const int y = r0 + wn;
  #pragma unroll
  for (int mf = 0; mf < 4; ++mf) {
    #pragma unroll
    for (int reg = 0; reg < 16; ++reg) {
      const int rowid = (reg & 3) + 8 * (reg >> 2) + 4 * laneK;
      const int oc = oc0 + 32 * mf + rowid;
      const float sc = scale[b * OUT_CH + oc];
      float* op = out + (((size_t)(b * OUT_CH + oc) * HW + y) * HW) + ln31;
      op[0] = acc[mf][0][reg] * sc;
      op[32] = acc[mf][1][reg] * sc;
    }
  }
}

// ---------------- launcher ---------------------------------------------------------------
extern "C" void kernel_launch(void* const* d_in, const int* in_sizes, int n_in,
                              void* d_out, int out_size, void* d_ws, size_t ws_size,
                              hipStream_t stream) {
  const float* x      = (const float*)d_in[0];
  const float* style  = (const float*)d_in[1];
  const float* weight = (const float*)d_in[2];
  const float* modw   = (const float*)d_in[3];
  const float* modb   = (const float*)d_in[4];
  float* out = (float*)d_out;

  char* ws = (char*)d_ws;
  float*  s_buf = (float*)(ws + 0);                        // 16 KB
  float*  scale = (float*)(ws + 16384);                    // 16 KB
  __bf16* zpg   = (__bf16*)(ws + 32768);                   // 16 KB zero page
  __bf16* wgp   = (__bf16*)(ws + 49152);                   // 9*16*4*512*16 B = 4.72 MB
  __bf16* xgp   = (__bf16*)(ws + 49152 + 9 * 16 * 4 * 512 * 16);  // 8*64*16*272*16 = 35.7 MB

  k_style<<<129, 256, 0, stream>>>(style, modw, modb, s_buf, (float*)zpg);
  k_prep<<<1088, 512, 0, stream>>>(x, s_buf, weight, xgp, wgp, scale);
  k_conv<<<512, 256, 0, stream>>>(wgp, xgp, scale, zpg, out);
}